// Round 1
// baseline (97.410 us; speedup 1.0000x reference)
//
#include <hip/hip_runtime.h>

#define HH 96
#define WW 96
#define NN (HH * WW)          // 9216
#define JSPLIT 16
#define JC (NN / JSPLIT)      // 576 j's per block
#define BLK 256

// Gaussian constants with log2(e) folded in so we can use native v_exp_f32 (exp2).
// CXY  = log2(e) / (2 * 15^2)    = 0.0032059890
// CRGB = log2(e) / (2 * 0.125^2) = 46.16624131
#define CXY 0.0032059890f
#define CRGB 46.16624131f

__global__ __launch_bounds__(BLK) void crf_pair_kernel(
    const float* __restrict__ probs,   // [2, N] (class-0 plane at offset 0)
    const float* __restrict__ image,   // [3, N]
    float* __restrict__ out)           // [1], pre-zeroed
{
    __shared__ float4 sj[JC];   // (r, g, b, s0) for the j-chunk
    __shared__ float2 syx[JC];  // (y, x) for the j-chunk

    const int tid = threadIdx.x;
    const int j0 = blockIdx.y * JC;

    // Stage this block's j-chunk into LDS.
    for (int t = tid; t < JC; t += BLK) {
        const int j = j0 + t;
        const int y = j / WW;
        const int x = j - y * WW;
        sj[t]  = make_float4(image[0 * NN + j], image[1 * NN + j],
                             image[2 * NN + j], probs[j]);
        syx[t] = make_float2((float)y, (float)x);
    }
    __syncthreads();

    // Per-thread i data.
    const int i   = blockIdx.x * BLK + tid;      // N == 36*256 exactly
    const int yii = i / WW;
    const float yi = (float)yii;
    const float xi = (float)(i - yii * WW);
    const float ri = image[0 * NN + i];
    const float gi = image[1 * NN + i];
    const float bi = image[2 * NN + i];
    const float ai = probs[i];
    const float ci = 1.0f - 2.0f * ai;           // w = a_i + a_j*(1 - 2a_i)

    float acc = 0.0f;
#pragma unroll 4
    for (int t = 0; t < JC; ++t) {
        const float4 q = sj[t];    // broadcast — conflict-free
        const float2 p = syx[t];
        const float dy = yi - p.x;
        const float dx = xi - p.y;
        const float dxy = fmaf(dy, dy, dx * dx);
        const float dr = ri - q.x;
        const float dg = gi - q.y;
        const float db = bi - q.z;
        const float drgb = fmaf(dr, dr, fmaf(dg, dg, db * db));
        const float arg = fmaf(dxy, -CXY, drgb * -CRGB);
        const float k = __builtin_amdgcn_exp2f(arg);      // v_exp_f32
        const float wv = fmaf(q.w, ci, ai);
        acc = fmaf(wv, k, acc);
    }

    // Wave (64-lane) shuffle reduction.
    for (int off = 32; off > 0; off >>= 1)
        acc += __shfl_down(acc, off, 64);

    __shared__ float wsum[BLK / 64];
    if ((tid & 63) == 0) wsum[tid >> 6] = acc;
    __syncthreads();
    if (tid == 0) {
        float s = 0.0f;
#pragma unroll
        for (int w = 0; w < BLK / 64; ++w) s += wsum[w];
        atomicAdd(out, s * (1.0f / (float)NN));
    }
}

extern "C" void kernel_launch(void* const* d_in, const int* in_sizes, int n_in,
                              void* d_out, int out_size, void* d_ws, size_t ws_size,
                              hipStream_t stream) {
    const float* probs = (const float*)d_in[0];  // [1,2,96,96] fp32
    const float* image = (const float*)d_in[1];  // [1,3,96,96] fp32
    float* out = (float*)d_out;                  // [1] fp32

    // d_out is poisoned (0xAA) before every timed launch — zero it on-stream.
    hipMemsetAsync(out, 0, sizeof(float), stream);

    dim3 grid(NN / BLK, JSPLIT);   // 36 x 16 = 576 blocks
    crf_pair_kernel<<<grid, dim3(BLK), 0, stream>>>(probs, image, out);
}

// Round 2
// 72.183 us; speedup vs baseline: 1.3495x; 1.3495x over previous
//
#include <hip/hip_runtime.h>

#define HH 96
#define WW 96
#define NN (HH * WW)            // 9216
#define TILE 1024               // i/j tile size
#define NT (NN / TILE)          // 9 tiles
#define NPAIRS (NT * (NT + 1) / 2)  // 45 tile-pairs (a <= b)
#define JSPLIT 16
#define JC (TILE / JSPLIT)      // 64 j's per block
#define BLK 256
#define M 4                     // i's per thread -> i-tile = M*BLK = 1024

// Gaussian constants with log2(e) folded in (native v_exp_f32 is exp2):
// CXY  = log2(e) / (2 * 15^2),  CRGB = log2(e) / (2 * 0.125^2)
#define CXY 0.0032059890f
#define CRGB 46.16624131f

// Expanded form: -CXY*|pi-pj|^2 - CRGB*|ci-cj|^2
//   = A_i + A_j + yi*(2CXY*yj) + xi*(2CXY*xj) + ri*(2CRGB*rj) + gi*(2CRGB*gj) + bi*(2CRGB*bj)
// with A_k = -CXY*(y^2+x^2) - CRGB*(r^2+g^2+b^2). All cross terms >= 0, so the
// fma chain rises monotonically from A_i+A_j (>= -392) to <= 0: no overflow.

__global__ __launch_bounds__(BLK) void crf_sym_kernel(
    const float* __restrict__ probs,   // [2, N], class-0 plane first
    const float* __restrict__ image,   // [3, N]
    float* __restrict__ out)           // [1], pre-zeroed
{
    __shared__ float4 sq1[JC];  // (2CXY*yj, 2CXY*xj, 2CRGB*rj, 2CRGB*gj)
    __shared__ float4 sq2[JC];  // (2CRGB*bj, Aj, aj, pad)

    // Decode tile-pair (a, b), a <= b, from blockIdx.x (block-uniform scalar loop).
    int p = blockIdx.x;
    int a = 0;
    while (p >= NT - a) { p -= NT - a; ++a; }
    const int b = a + p;

    const int tid = threadIdx.x;

    // Stage the 64-j chunk of tile b into LDS.
    if (tid < JC) {
        const int j  = b * TILE + blockIdx.y * JC + tid;
        const int yj = j / WW;
        const float fy = (float)yj;
        const float fx = (float)(j - yj * WW);
        const float r  = image[j];
        const float g  = image[NN + j];
        const float bl = image[2 * NN + j];
        const float aj = probs[j];
        const float Aj = -CXY * fmaf(fy, fy, fx * fx)
                         - CRGB * fmaf(r, r, fmaf(g, g, bl * bl));
        sq1[tid] = make_float4(2.0f * CXY * fy, 2.0f * CXY * fx,
                               2.0f * CRGB * r, 2.0f * CRGB * g);
        sq2[tid] = make_float4(2.0f * CRGB * bl, Aj, aj, 0.0f);
    }

    // Per-thread i data: M coalesced i's from tile a.
    float yi[M], xi[M], ri[M], gi[M], bi[M], ai[M], ci[M], Ai[M], acc[M];
#pragma unroll
    for (int m = 0; m < M; ++m) {
        const int i  = a * TILE + m * BLK + tid;
        const int yy = i / WW;
        yi[m] = (float)yy;
        xi[m] = (float)(i - yy * WW);
        ri[m] = image[i];
        gi[m] = image[NN + i];
        bi[m] = image[2 * NN + i];
        ai[m] = probs[i];
        ci[m] = fmaf(-2.0f, ai[m], 1.0f);   // 1 - 2*ai
        Ai[m] = -CXY * fmaf(yi[m], yi[m], xi[m] * xi[m])
                - CRGB * fmaf(ri[m], ri[m], fmaf(gi[m], gi[m], bi[m] * bi[m]));
        acc[m] = 0.0f;
    }

    __syncthreads();

#pragma unroll 2
    for (int t = 0; t < JC; ++t) {
        const float4 q1 = sq1[t];   // broadcast, conflict-free
        const float4 q2 = sq2[t];
#pragma unroll
        for (int m = 0; m < M; ++m) {
            float arg = Ai[m] + q2.y;
            arg = fmaf(yi[m], q1.x, arg);
            arg = fmaf(xi[m], q1.y, arg);
            arg = fmaf(ri[m], q1.z, arg);
            arg = fmaf(gi[m], q1.w, arg);
            arg = fmaf(bi[m], q2.x, arg);
            const float k  = __builtin_amdgcn_exp2f(arg);
            const float wv = fmaf(q2.z, ci[m], ai[m]);  // ai + aj*(1-2ai)
            acc[m] = fmaf(wv, k, acc[m]);
        }
    }

    // Reduce: thread -> wave (64) -> block -> global atomic.
    float s = (acc[0] + acc[1]) + (acc[2] + acc[3]);
    for (int off = 32; off > 0; off >>= 1)
        s += __shfl_down(s, off, 64);

    __shared__ float wsum[BLK / 64];
    if ((tid & 63) == 0) wsum[tid >> 6] = s;
    __syncthreads();
    if (tid == 0) {
        float bs = 0.0f;
#pragma unroll
        for (int w = 0; w < BLK / 64; ++w) bs += wsum[w];
        const float weight = (a == b) ? 1.0f : 2.0f;   // symmetry: off-diag counted twice
        atomicAdd(out, bs * (weight / (float)NN));
    }
}

extern "C" void kernel_launch(void* const* d_in, const int* in_sizes, int n_in,
                              void* d_out, int out_size, void* d_ws, size_t ws_size,
                              hipStream_t stream) {
    const float* probs = (const float*)d_in[0];  // [1,2,96,96] fp32
    const float* image = (const float*)d_in[1];  // [1,3,96,96] fp32
    float* out = (float*)d_out;                  // [1] fp32

    // d_out is poisoned (0xAA) before every timed launch — zero it on-stream.
    hipMemsetAsync(out, 0, sizeof(float), stream);

    dim3 grid(NPAIRS, JSPLIT);   // 45 x 16 = 720 blocks
    crf_sym_kernel<<<grid, dim3(BLK), 0, stream>>>(probs, image, out);
}